// Round 1
// baseline (718.946 us; speedup 1.0000x reference)
//
#include <hip/hip_runtime.h>
#include <hip/hip_bf16.h>
#include <cmath>

// Problem constants
#define BSZ      256
#define D_IN     2048
#define D_OUT    2048
#define MG       1024      // M_GROUPS
#define NC       8         // N_CELLS
#define TOTAL    8192      // MG*NC
#define KGRP     128       // K_GROUPS (top-k groups)

// ---------------------------------------------------------------------------
// Tiled FP32 GEMM: C[M,N] = A[M,K] @ B[K,N] + bias[N]  (+ optional repeat-add)
// MODE 0: C = A@B + bias
// MODE 1: C = aux[m][n/8] + (A@B + bias)   (sigma = z_a repeated + z_b)
// Tile 64x64, BK=32, 256 threads, 4x4 per thread.
// ---------------------------------------------------------------------------
#define TILE 64
#define BK   32

template <int MODE>
__global__ __launch_bounds__(256) void gemm_f32(
    const float* __restrict__ A, const float* __restrict__ B,
    const float* __restrict__ bias, const float* __restrict__ aux,
    float* __restrict__ C, int M, int N, int K)
{
    // A-tile stored transposed, padded to keep float4 reads 16B-aligned
    __shared__ float As[BK][TILE + 4];   // stride 68 floats (272B, 16B-aligned)
    __shared__ float Bs[BK][TILE];

    const int tid = threadIdx.x;
    const int tx = tid & 15;   // N direction (4 cols each)
    const int ty = tid >> 4;   // M direction (4 rows each)
    const int n0 = blockIdx.x * TILE;
    const int m0 = blockIdx.y * TILE;

    float acc[4][4] = {};

    for (int k0 = 0; k0 < K; k0 += BK) {
        // Load A tile: 64 rows x 32 k  (8 float4 per row -> 512 float4, 2/thread)
        #pragma unroll
        for (int it = 0; it < 2; ++it) {
            int lin = tid + it * 256;
            int row = lin >> 3;
            int c4  = lin & 7;
            float4 a = *(const float4*)&A[(size_t)(m0 + row) * K + k0 + c4 * 4];
            As[c4 * 4 + 0][row] = a.x;
            As[c4 * 4 + 1][row] = a.y;
            As[c4 * 4 + 2][row] = a.z;
            As[c4 * 4 + 3][row] = a.w;
        }
        // Load B tile: 32 k x 64 cols (16 float4 per row -> 512 float4, 2/thread)
        #pragma unroll
        for (int it = 0; it < 2; ++it) {
            int lin = tid + it * 256;
            int row = lin >> 4;
            int c4  = lin & 15;
            *(float4*)&Bs[row][c4 * 4] =
                *(const float4*)&B[(size_t)(k0 + row) * N + n0 + c4 * 4];
        }
        __syncthreads();

        #pragma unroll
        for (int k = 0; k < BK; ++k) {
            float4 av = *(const float4*)&As[k][ty * 4];
            float4 bv = *(const float4*)&Bs[k][tx * 4];
            float a_[4] = {av.x, av.y, av.z, av.w};
            float b_[4] = {bv.x, bv.y, bv.z, bv.w};
            #pragma unroll
            for (int i = 0; i < 4; ++i)
                #pragma unroll
                for (int j = 0; j < 4; ++j)
                    acc[i][j] = fmaf(a_[i], b_[j], acc[i][j]);
        }
        __syncthreads();
    }

    // Epilogue
    #pragma unroll
    for (int i = 0; i < 4; ++i) {
        int m = m0 + ty * 4 + i;
        int n = n0 + tx * 4;
        float4 out;
        float* o = (float*)&out;
        #pragma unroll
        for (int j = 0; j < 4; ++j) {
            float v = acc[i][j] + bias[n + j];
            if (MODE == 1) v = aux[(size_t)m * MG + ((n + j) >> 3)] + v;
            o[j] = v;
        }
        *(float4*)&C[(size_t)m * N + n] = out;
    }
}

// ---------------------------------------------------------------------------
// Deterministic two-stage min reduction
// ---------------------------------------------------------------------------
__global__ __launch_bounds__(256) void block_min(
    const float* __restrict__ x, int n, float* __restrict__ out)
{
    __shared__ float red[256];
    float v = 3.402823466e+38f;
    for (int i = blockIdx.x * 256 + threadIdx.x; i < n; i += gridDim.x * 256)
        v = fminf(v, x[i]);
    red[threadIdx.x] = v;
    __syncthreads();
    for (int s = 128; s > 0; s >>= 1) {
        if (threadIdx.x < s)
            red[threadIdx.x] = fminf(red[threadIdx.x], red[threadIdx.x + s]);
        __syncthreads();
    }
    if (threadIdx.x == 0) out[blockIdx.x] = red[0];
}

// ---------------------------------------------------------------------------
// Per-row kernel: pi -> per-group top-1 + lambda -> per-row top-128 groups
// -> y, phi_new/psi_new/x_b_new, decode_in
// One block per batch row, 256 threads.
// ---------------------------------------------------------------------------
__global__ __launch_bounds__(256) void row_kernel(
    const float* __restrict__ sigma, const float* __restrict__ phi,
    const float* __restrict__ psi, const float* __restrict__ minval,
    float* __restrict__ decode, float* __restrict__ xb_new,
    float* __restrict__ phi_new, float* __restrict__ psi_new)
{
    __shared__ unsigned long long keys[MG];  // (lambda desc, group asc) sort keys
    __shared__ int acell[MG];                // per-group argmax cell
    __shared__ int win[MG];                  // per-group winner flag

    const int b = blockIdx.x;
    const int tid = threadIdx.x;
    const float smin = minval[0];
    const float* srow = sigma + (size_t)b * TOTAL;
    const float* prow = phi + (size_t)b * TOTAL;
    const float* qrow = psi + (size_t)b * TOTAL;

    // Phase A: per-group lambda (max of pi) + argmax cell (first index on ties)
    for (int g = tid; g < MG; g += 256) {
        float best = -3.402823466e+38f;
        int bc = 0;
        #pragma unroll
        for (int c = 0; c < NC; ++c) {
            float s = srow[g * NC + c];
            float p = prow[g * NC + c];
            float pi = (1.0f - p) * ((s - smin) + 1.0f);
            if (pi > best) { best = pi; bc = c; }
        }
        unsigned int bits = __float_as_uint(best);
        unsigned int u = (bits & 0x80000000u) ? ~bits : (bits | 0x80000000u);
        // ascending sort key: descending lambda, tie -> ascending group index
        keys[g] = ((unsigned long long)(~u) << 32) | (unsigned int)g;
        acell[g] = bc;
        win[g] = 0;
    }
    __syncthreads();

    // Phase B: bitonic ascending sort of 1024 distinct keys
    for (int k = 2; k <= MG; k <<= 1) {
        for (int j = k >> 1; j > 0; j >>= 1) {
            for (int t = tid; t < MG; t += 256) {
                int ixj = t ^ j;
                if (ixj > t) {
                    unsigned long long a = keys[t], bb_ = keys[ixj];
                    bool asc = ((t & k) == 0);
                    if ((a > bb_) == asc) { keys[t] = bb_; keys[ixj] = a; }
                }
            }
            __syncthreads();
        }
    }
    // First 128 keys = winning groups
    if (tid < KGRP) {
        int g = (int)(keys[tid] & 0xFFFFFFFFu);
        win[g] = 1;
    }
    __syncthreads();

    // Phase C: y + elementwise outputs (GAMMA = EPS = 0.5, PRED_GAIN = 1)
    for (int j = tid; j < TOTAL; j += 256) {
        int g = j >> 3, c = j & 7;
        float s = srow[j];
        float y = 0.0f;
        if (win[g] && acell[g] == c) y = tanhf(s);
        float pn = fmaxf(prow[j] * 0.5f, y);
        float qn = fmaxf(qrow[j] * 0.5f, y);
        phi_new[(size_t)b * TOTAL + j] = pn;
        psi_new[(size_t)b * TOTAL + j] = qn;
        xb_new[(size_t)b * TOTAL + j] = qn;
    }

    // Phase D: decode_in = group max of y = win ? max(0, tanh(sigma_sel)) : 0
    for (int g = tid; g < MG; g += 256) {
        float d = 0.0f;
        if (win[g]) d = fmaxf(0.0f, tanhf(srow[g * NC + acell[g]]));
        decode[(size_t)b * MG + g] = d;
    }
}

// ---------------------------------------------------------------------------
extern "C" void kernel_launch(void* const* d_in, const int* in_sizes, int n_in,
                              void* d_out, int out_size, void* d_ws, size_t ws_size,
                              hipStream_t stream)
{
    const float* x_a = (const float*)d_in[0];
    const float* x_b = (const float*)d_in[1];
    const float* phi = (const float*)d_in[2];
    const float* psi = (const float*)d_in[3];
    const float* Wa  = (const float*)d_in[4];
    const float* ba  = (const float*)d_in[5];
    const float* Wb  = (const float*)d_in[6];
    const float* bb  = (const float*)d_in[7];
    const float* Wd  = (const float*)d_in[8];
    const float* bd  = (const float*)d_in[9];

    float* out = (float*)d_out;
    float* pred    = out;                                  // 256*2048
    float* xb_new  = out + BSZ * D_OUT;                    // 256*8192
    float* phi_new = out + BSZ * D_OUT + BSZ * TOTAL;      // 256*8192
    float* psi_new = out + BSZ * D_OUT + 2 * BSZ * TOTAL;  // 256*8192

    float* ws = (float*)d_ws;
    float* z_a    = ws;                                    // 262144
    float* sigma  = ws + 262144;                           // 2097152
    float* decode = ws + 262144 + 2097152;                 // 262144
    float* bmin   = ws + 2621440;                          // 1024
    float* minv   = ws + 2622464;                          // 1
    // total workspace: ~10.5 MB

    dim3 blk(256);

    // z_a = x_a @ Wa + ba            [256,1024], K=2048
    gemm_f32<0><<<dim3(MG / TILE, BSZ / TILE), blk, 0, stream>>>(
        x_a, Wa, ba, nullptr, z_a, BSZ, MG, D_IN);

    // sigma = repeat(z_a,8) + x_b @ Wb + bb    [256,8192], K=8192
    gemm_f32<1><<<dim3(TOTAL / TILE, BSZ / TILE), blk, 0, stream>>>(
        x_b, Wb, bb, z_a, sigma, BSZ, TOTAL, TOTAL);

    // global min of sigma (deterministic two-stage)
    block_min<<<1024, blk, 0, stream>>>(sigma, BSZ * TOTAL, bmin);
    block_min<<<1, blk, 0, stream>>>(bmin, 1024, minv);

    // masks, y, elementwise outputs, decode_in
    row_kernel<<<BSZ, blk, 0, stream>>>(
        sigma, phi, psi, minv, decode, xb_new, phi_new, psi_new);

    // pred = decode @ Wd + bd        [256,2048], K=1024
    gemm_f32<0><<<dim3(D_OUT / TILE, BSZ / TILE), blk, 0, stream>>>(
        decode, Wd, bd, nullptr, pred, BSZ, D_OUT, MG);
}

// Round 3
// 363.575 us; speedup vs baseline: 1.9774x; 1.9774x over previous
//
#include <hip/hip_runtime.h>
#include <hip/hip_bf16.h>
#include <cmath>

// Problem constants
#define BSZ      256
#define D_IN     2048
#define D_OUT    2048
#define MG       1024      // M_GROUPS
#define NC       8         // N_CELLS
#define TOTAL    8192      // MG*NC
#define KGRP     128       // K_GROUPS (top-k groups)

typedef short bf16x8 __attribute__((ext_vector_type(8)));
typedef short s16x4  __attribute__((ext_vector_type(4)));
typedef float f32x4  __attribute__((ext_vector_type(4)));

// fp32 <-> bf16 helpers (round-to-nearest-even, bit ops, deterministic)
__device__ inline short f2bf(float f) {
    unsigned u = __float_as_uint(f);
    unsigned r = (u + 0x7fffu + ((u >> 16) & 1u)) >> 16;
    return (short)r;
}
__device__ inline float bf2f(short s) {
    return __uint_as_float(((unsigned)(unsigned short)s) << 16);
}

// ===========================================================================
// fp32 path (small GEMMs + fallback)
// ===========================================================================
#define TILE 64
#define BK   32

template <int MODE>
__global__ __launch_bounds__(256) void gemm_f32(
    const float* __restrict__ A, const float* __restrict__ B,
    const float* __restrict__ bias, const float* __restrict__ aux,
    float* __restrict__ C, int M, int N, int K)
{
    __shared__ float As[BK][TILE + 4];
    __shared__ float Bs[BK][TILE];

    const int tid = threadIdx.x;
    const int tx = tid & 15;
    const int ty = tid >> 4;
    const int n0 = blockIdx.x * TILE;
    const int m0 = blockIdx.y * TILE;

    float acc[4][4] = {};

    for (int k0 = 0; k0 < K; k0 += BK) {
        #pragma unroll
        for (int it = 0; it < 2; ++it) {
            int lin = tid + it * 256;
            int row = lin >> 3;
            int c4  = lin & 7;
            float4 a = *(const float4*)&A[(size_t)(m0 + row) * K + k0 + c4 * 4];
            As[c4 * 4 + 0][row] = a.x;
            As[c4 * 4 + 1][row] = a.y;
            As[c4 * 4 + 2][row] = a.z;
            As[c4 * 4 + 3][row] = a.w;
        }
        #pragma unroll
        for (int it = 0; it < 2; ++it) {
            int lin = tid + it * 256;
            int row = lin >> 4;
            int c4  = lin & 15;
            *(float4*)&Bs[row][c4 * 4] =
                *(const float4*)&B[(size_t)(k0 + row) * N + n0 + c4 * 4];
        }
        __syncthreads();

        #pragma unroll
        for (int k = 0; k < BK; ++k) {
            float4 av = *(const float4*)&As[k][ty * 4];
            float4 bv = *(const float4*)&Bs[k][tx * 4];
            float a_[4] = {av.x, av.y, av.z, av.w};
            float b_[4] = {bv.x, bv.y, bv.z, bv.w};
            #pragma unroll
            for (int i = 0; i < 4; ++i)
                #pragma unroll
                for (int j = 0; j < 4; ++j)
                    acc[i][j] = fmaf(a_[i], b_[j], acc[i][j]);
        }
        __syncthreads();
    }

    #pragma unroll
    for (int i = 0; i < 4; ++i) {
        int m = m0 + ty * 4 + i;
        int n = n0 + tx * 4;
        float4 out;
        float* o = (float*)&out;
        #pragma unroll
        for (int j = 0; j < 4; ++j) {
            float v = acc[i][j] + bias[n + j];
            if (MODE == 1) v = aux[(size_t)m * MG + ((n + j) >> 3)] + v;
            o[j] = v;
        }
        *(float4*)&C[(size_t)m * N + n] = out;
    }
}

__global__ __launch_bounds__(256) void block_min(
    const float* __restrict__ x, int n, float* __restrict__ out)
{
    __shared__ float red[256];
    float v = 3.402823466e+38f;
    for (int i = blockIdx.x * 256 + threadIdx.x; i < n; i += gridDim.x * 256)
        v = fminf(v, x[i]);
    red[threadIdx.x] = v;
    __syncthreads();
    for (int s = 128; s > 0; s >>= 1) {
        if (threadIdx.x < s)
            red[threadIdx.x] = fminf(red[threadIdx.x], red[threadIdx.x + s]);
        __syncthreads();
    }
    if (threadIdx.x == 0) out[blockIdx.x] = red[0];
}

__global__ __launch_bounds__(256) void row_kernel(
    const float* __restrict__ sigma, const float* __restrict__ phi,
    const float* __restrict__ psi, const float* __restrict__ minval,
    float* __restrict__ decode, float* __restrict__ xb_new,
    float* __restrict__ phi_new, float* __restrict__ psi_new)
{
    __shared__ unsigned long long keys[MG];
    __shared__ int acell[MG];
    __shared__ int win[MG];

    const int b = blockIdx.x;
    const int tid = threadIdx.x;
    const float smin = minval[0];
    const float* srow = sigma + (size_t)b * TOTAL;
    const float* prow = phi + (size_t)b * TOTAL;
    const float* qrow = psi + (size_t)b * TOTAL;

    for (int g = tid; g < MG; g += 256) {
        float best = -3.402823466e+38f;
        int bc = 0;
        #pragma unroll
        for (int c = 0; c < NC; ++c) {
            float s = srow[g * NC + c];
            float p = prow[g * NC + c];
            float pi = (1.0f - p) * ((s - smin) + 1.0f);
            if (pi > best) { best = pi; bc = c; }
        }
        unsigned int bits = __float_as_uint(best);
        unsigned int u = (bits & 0x80000000u) ? ~bits : (bits | 0x80000000u);
        keys[g] = ((unsigned long long)(~u) << 32) | (unsigned int)g;
        acell[g] = bc;
        win[g] = 0;
    }
    __syncthreads();

    for (int k = 2; k <= MG; k <<= 1) {
        for (int j = k >> 1; j > 0; j >>= 1) {
            for (int t = tid; t < MG; t += 256) {
                int ixj = t ^ j;
                if (ixj > t) {
                    unsigned long long a = keys[t], bb_ = keys[ixj];
                    bool asc = ((t & k) == 0);
                    if ((a > bb_) == asc) { keys[t] = bb_; keys[ixj] = a; }
                }
            }
            __syncthreads();
        }
    }
    if (tid < KGRP) {
        int g = (int)(keys[tid] & 0xFFFFFFFFu);
        win[g] = 1;
    }
    __syncthreads();

    for (int j = tid; j < TOTAL; j += 256) {
        int g = j >> 3, c = j & 7;
        float s = srow[j];
        float y = 0.0f;
        if (win[g] && acell[g] == c) y = tanhf(s);
        float pn = fmaxf(prow[j] * 0.5f, y);
        float qn = fmaxf(qrow[j] * 0.5f, y);
        phi_new[(size_t)b * TOTAL + j] = pn;
        psi_new[(size_t)b * TOTAL + j] = qn;
        xb_new[(size_t)b * TOTAL + j] = qn;
    }

    for (int g = tid; g < MG; g += 256) {
        float d = 0.0f;
        if (win[g]) d = fmaxf(0.0f, tanhf(srow[g * NC + acell[g]]));
        decode[(size_t)b * MG + g] = d;
    }
}

// ===========================================================================
// bf16x3 MFMA path for the sigma GEMM (hi*hi + hi*lo + lo*hi)
// ===========================================================================

// Convert x_b -> bf16 hi/lo planes (plain layout, no swizzle).
__global__ __launch_bounds__(256) void convert_xb(
    const float* __restrict__ xb, short* __restrict__ xh, short* __restrict__ xl)
{
    int t = blockIdx.x * 256 + threadIdx.x;   // 262144 chunks of 8
    size_t idx = (size_t)t * 8;
    float4 v0 = *(const float4*)&xb[idx];
    float4 v1 = *(const float4*)&xb[idx + 4];
    float vv[8] = {v0.x, v0.y, v0.z, v0.w, v1.x, v1.y, v1.z, v1.w};
    bf16x8 h, l;
    #pragma unroll
    for (int e = 0; e < 8; ++e) {
        short hh = f2bf(vv[e]);
        h[e] = hh;
        l[e] = f2bf(vv[e] - bf2f(hh));
    }
    *(bf16x8*)&xh[idx] = h;
    *(bf16x8*)&xl[idx] = l;
}

// partial[ks] = x_b[:, ks*2048:(ks+1)*2048] @ Wb[same k rows, :]
// BM=256 (all rows), BN=64, BK=64, K-split 4. 4 waves; wave w owns rows
// [w*64, w*64+64). Static 80 KB LDS. All LDS ops compiler-visible, XOR-
// swizzled at 8-element-chunk granularity (bijective, conflict-free b128).
#define GBN   64
#define GBK   64
#define KSPL  4
#define KPER  (TOTAL / KSPL)   // 2048

__global__ __launch_bounds__(256, 2) void gemm_sigma(
    const short* __restrict__ xh, const short* __restrict__ xl,
    const float* __restrict__ Wb, float* __restrict__ partial)
{
    // A: [row][64k], chunk c (of 8 elems) stored at position c ^ (row&7)
    __shared__ short Ah[256 * 64];   // 32 KB
    __shared__ short Al[256 * 64];   // 32 KB
    // B (transposed): [n][64k], chunk kc stored at position kc ^ (n&7)
    __shared__ short Bh[64 * 64];    // 8 KB
    __shared__ short Bl[64 * 64];    // 8 KB  -> total 80 KB static

    const int tid = threadIdx.x;
    const int l = tid & 63;
    const int w = tid >> 6;
    const int n0 = blockIdx.x * GBN;
    const int k0 = blockIdx.y * KPER;

    f32x4 acc[4][4] = {};

    for (int st = 0; st < KPER / GBK; ++st) {
        const int kw = k0 + st * GBK;

        // ---- Stage A: rows 0..255 x 64 k, hi+lo (reg-staged, swizzled write)
        {
            int row8 = tid >> 3;            // 0..31
            int c = tid & 7;                // chunk within k-window
            #pragma unroll
            for (int sub = 0; sub < 8; ++sub) {
                int row = row8 + sub * 32;
                size_t g = (size_t)row * TOTAL + kw + c * 8;
                int dst = row * 64 + ((c ^ (row & 7)) * 8);
                *(bf16x8*)&Ah[dst] = *(const bf16x8*)&xh[g];
                *(bf16x8*)&Al[dst] = *(const bf16x8*)&xl[g];
            }
        }
        // ---- Stage B: wave w covers k = w*16..w*16+15, lane covers n = l
        {
            int n = l;
            #pragma unroll
            for (int jj = 0; jj < 2; ++jj) {
                int kc = w * 2 + jj;        // 8-k chunk index (0..7)
                s16x4 hv[2], lv[2];
                #pragma unroll
                for (int j = 0; j < 8; ++j) {
                    int k = kc * 8 + j;
                    float v = Wb[(size_t)(kw + k) * TOTAL + n0 + n];
                    short hh = f2bf(v);
                    hv[j >> 2][j & 3] = hh;
                    lv[j >> 2][j & 3] = f2bf(v - bf2f(hh));
                }
                int base = n * 64 + ((kc ^ (n & 7)) * 8);
                *(s16x4*)&Bh[base]     = hv[0];
                *(s16x4*)&Bh[base + 4] = hv[1];
                *(s16x4*)&Bl[base]     = lv[0];
                *(s16x4*)&Bl[base + 4] = lv[1];
            }
        }
        __syncthreads();

        // ---- Compute: 2 sub-k of 32; per wave 4x4 fragment tiles, 3 products
        #pragma unroll
        for (int kk = 0; kk < 2; ++kk) {
            bf16x8 ah[4], al[4], bh[4], bl[4];
            #pragma unroll
            for (int mt = 0; mt < 4; ++mt) {
                int row = w * 64 + mt * 16 + (l & 15);
                int pos = (kk * 4 + (l >> 4)) ^ (row & 7);
                ah[mt] = *(const bf16x8*)&Ah[row * 64 + pos * 8];
                al[mt] = *(const bf16x8*)&Al[row * 64 + pos * 8];
            }
            #pragma unroll
            for (int nt = 0; nt < 4; ++nt) {
                int n = nt * 16 + (l & 15);
                int pos = (kk * 4 + (l >> 4)) ^ (n & 7);
                bh[nt] = *(const bf16x8*)&Bh[n * 64 + pos * 8];
                bl[nt] = *(const bf16x8*)&Bl[n * 64 + pos * 8];
            }
            #pragma unroll
            for (int mt = 0; mt < 4; ++mt)
                #pragma unroll
                for (int nt = 0; nt < 4; ++nt) {
                    acc[mt][nt] = __builtin_amdgcn_mfma_f32_16x16x32_bf16(
                        ah[mt], bh[nt], acc[mt][nt], 0, 0, 0);
                    acc[mt][nt] = __builtin_amdgcn_mfma_f32_16x16x32_bf16(
                        ah[mt], bl[nt], acc[mt][nt], 0, 0, 0);
                    acc[mt][nt] = __builtin_amdgcn_mfma_f32_16x16x32_bf16(
                        al[mt], bh[nt], acc[mt][nt], 0, 0, 0);
                }
        }
        __syncthreads();
    }

    // Epilogue: D layout col = lane&15, row = (lane>>4)*4 + reg
    float* P = partial + (size_t)blockIdx.y * BSZ * TOTAL;
    #pragma unroll
    for (int mt = 0; mt < 4; ++mt) {
        int m = w * 64 + mt * 16 + (l >> 4) * 4;
        #pragma unroll
        for (int nt = 0; nt < 4; ++nt) {
            int n = n0 + nt * 16 + (l & 15);
            #pragma unroll
            for (int r = 0; r < 4; ++r)
                P[(size_t)(m + r) * TOTAL + n] = acc[mt][nt][r];
        }
    }
}

// sigma = p0+p1+p2+p3 + repeat(z_a,8) + bb ; fused per-block min -> bmin
__global__ __launch_bounds__(256) void reduce_sigma_min(
    const float* __restrict__ partial, const float* __restrict__ z_a,
    const float* __restrict__ bb, float* __restrict__ sigma,
    float* __restrict__ bmin)
{
    __shared__ float red[256];
    int i = blockIdx.x * 256 + threadIdx.x;       // float4 index
    size_t b4 = (size_t)i * 4;
    const size_t stride4 = (size_t)BSZ * TOTAL / 4;
    const float4* p = (const float4*)partial;
    float4 s0 = p[i], s1 = p[i + stride4], s2 = p[i + 2 * stride4], s3 = p[i + 3 * stride4];
    int m = (int)(b4 >> 13);
    int n = (int)(b4 & 8191);
    float za = z_a[m * MG + (n >> 3)];
    float4 bias = *(const float4*)&bb[n];
    float4 s;
    s.x = ((s0.x + s1.x) + s2.x) + s3.x + za + bias.x;
    s.y = ((s0.y + s1.y) + s2.y) + s3.y + za + bias.y;
    s.z = ((s0.z + s1.z) + s2.z) + s3.z + za + bias.z;
    s.w = ((s0.w + s1.w) + s2.w) + s3.w + za + bias.w;
    *(float4*)&sigma[b4] = s;

    float v = fminf(fminf(s.x, s.y), fminf(s.z, s.w));
    red[threadIdx.x] = v;
    __syncthreads();
    for (int st = 128; st > 0; st >>= 1) {
        if (threadIdx.x < st)
            red[threadIdx.x] = fminf(red[threadIdx.x], red[threadIdx.x + st]);
        __syncthreads();
    }
    if (threadIdx.x == 0) bmin[blockIdx.x] = red[0];
}

// ---------------------------------------------------------------------------
extern "C" void kernel_launch(void* const* d_in, const int* in_sizes, int n_in,
                              void* d_out, int out_size, void* d_ws, size_t ws_size,
                              hipStream_t stream)
{
    const float* x_a = (const float*)d_in[0];
    const float* x_b = (const float*)d_in[1];
    const float* phi = (const float*)d_in[2];
    const float* psi = (const float*)d_in[3];
    const float* Wa  = (const float*)d_in[4];
    const float* ba  = (const float*)d_in[5];
    const float* Wb  = (const float*)d_in[6];
    const float* bb  = (const float*)d_in[7];
    const float* Wd  = (const float*)d_in[8];
    const float* bd  = (const float*)d_in[9];

    float* out = (float*)d_out;
    float* pred    = out;
    float* xb_new  = out + BSZ * D_OUT;
    float* phi_new = out + BSZ * D_OUT + BSZ * TOTAL;
    float* psi_new = out + BSZ * D_OUT + 2 * BSZ * TOTAL;

    float* ws = (float*)d_ws;
    dim3 blk(256);

    // Workspace layout (floats)
    const size_t OFF_ZA     = 0;            // 262144
    const size_t OFF_SIGMA  = 262144;       // 2097152
    const size_t OFF_DECODE = 2359296;      // 262144
    const size_t OFF_BMIN   = 2621440;      // 2048
    const size_t OFF_MINV   = 2623488;      // 16
    const size_t OFF_XH     = 2623504;      // 1048576 floats (2M shorts)
    const size_t OFF_XL     = 3672080;      // 1048576
    const size_t OFF_PART   = 4720656;      // 8388608
    const size_t NEED_BYTES = (OFF_PART + 8388608) * 4;   // ~52.4 MB

    if (ws_size >= NEED_BYTES) {
        float* z_a    = ws + OFF_ZA;
        float* sigma  = ws + OFF_SIGMA;
        float* decode = ws + OFF_DECODE;
        float* bmin   = ws + OFF_BMIN;
        float* minv   = ws + OFF_MINV;
        short* xh     = (short*)(ws + OFF_XH);
        short* xl     = (short*)(ws + OFF_XL);
        float* part   = ws + OFF_PART;

        gemm_f32<0><<<dim3(MG / TILE, BSZ / TILE), blk, 0, stream>>>(
            x_a, Wa, ba, nullptr, z_a, BSZ, MG, D_IN);

        convert_xb<<<1024, blk, 0, stream>>>(x_b, xh, xl);

        gemm_sigma<<<dim3(TOTAL / GBN, KSPL), blk, 0, stream>>>(xh, xl, Wb, part);

        reduce_sigma_min<<<2048, blk, 0, stream>>>(part, z_a, bb, sigma, bmin);
        block_min<<<1, blk, 0, stream>>>(bmin, 2048, minv);

        row_kernel<<<BSZ, blk, 0, stream>>>(
            sigma, phi, psi, minv, decode, xb_new, phi_new, psi_new);

        gemm_f32<0><<<dim3(D_OUT / TILE, BSZ / TILE), blk, 0, stream>>>(
            decode, Wd, bd, nullptr, pred, BSZ, D_OUT, MG);
    } else {
        // Fallback: proven fp32 path (needs ~10.5 MB ws)
        float* z_a    = ws;
        float* sigma  = ws + 262144;
        float* decode = ws + 262144 + 2097152;
        float* bmin   = ws + 2621440;
        float* minv   = ws + 2622464;

        gemm_f32<0><<<dim3(MG / TILE, BSZ / TILE), blk, 0, stream>>>(
            x_a, Wa, ba, nullptr, z_a, BSZ, MG, D_IN);
        gemm_f32<1><<<dim3(TOTAL / TILE, BSZ / TILE), blk, 0, stream>>>(
            x_b, Wb, bb, z_a, sigma, BSZ, TOTAL, TOTAL);
        block_min<<<1024, blk, 0, stream>>>(sigma, BSZ * TOTAL, bmin);
        block_min<<<1, blk, 0, stream>>>(bmin, 1024, minv);
        row_kernel<<<BSZ, blk, 0, stream>>>(
            sigma, phi, psi, minv, decode, xb_new, phi_new, psi_new);
        gemm_f32<0><<<dim3(D_OUT / TILE, BSZ / TILE), blk, 0, stream>>>(
            decode, Wd, bd, nullptr, pred, BSZ, D_OUT, MG);
    }
}